// Round 10
// baseline (351.048 us; speedup 1.0000x reference)
//
#include <hip/hip_runtime.h>
#include <cstdint>
#include <cstddef>

#define NNODES 50000
#define NEDGES 500000
#define NTOT (NEDGES + NNODES)
#define HDIM 128
#define CDIM 64
#define GDIM 64
#define NB 250      // buckets
#define NPB 200     // nodes per bucket
#define CHUNK 2048  // edges per partition block
#define NCHB ((NEDGES + CHUNK - 1) / CHUNK)

typedef __bf16 bf16x8 __attribute__((ext_vector_type(8)));
typedef __bf16 bf16x2 __attribute__((ext_vector_type(2)));
typedef float f32x4 __attribute__((ext_vector_type(4)));

// ================= setup: weight casts + Wa vectors + zero p =================

__global__ __launch_bounds__(256) void k_setup(const float* __restrict__ convW,
                                               const float* __restrict__ w1,
                                               const float* __restrict__ w2,
                                               const float* __restrict__ a_s,
                                               const float* __restrict__ a_d,
                                               __bf16* __restrict__ WtC,
                                               __bf16* __restrict__ Wt1,
                                               __bf16* __restrict__ Wt2,
                                               float* __restrict__ Wa,
                                               float* __restrict__ p) {
    int b = blockIdx.x, tid = threadIdx.x;
    if (b < 128) {
        int i = b * 256 + tid;
        int mat = i >> 14, rem = i & 16383;
        int k = rem >> 7, n = rem & 127;
        WtC[mat * 16384 + n * 128 + k] = (__bf16)convW[i];
    } else if (b < 192) {
        int i = (b - 128) * 256 + tid;
        int k = i >> 7, n = i & 127;
        Wt1[n * 128 + k] = (__bf16)w1[i];
    } else if (b < 224) {
        int i = (b - 192) * 256 + tid;
        int k = i >> 6, n = i & 63;
        Wt2[n * 128 + k] = (__bf16)w2[i];
    } else if (b == 224) {
        for (int o = tid; o < 512; o += 256) {
            int l = o >> 8, r = o & 255;
            int type = r >> 7, k = r & 127;
            const float* a = (type ? a_d : a_s) + l * 128;
            const float* Wrow = convW + l * 16384 + k * 128;
            float s = 0.f;
            for (int j = 0; j < 128; j++) s += Wrow[j] * a[j];
            Wa[o] = s;
        }
    } else {
        for (int i = tid; i < 2 * GDIM * CDIM; i += 256) p[i] = 0.f;
    }
}

// ================= CSR build via 2-level bucket sort (y = branch) =================

__global__ __launch_bounds__(256) void k_bhist(const int* __restrict__ ei0,
                                               const int* __restrict__ ei1,
                                               int* __restrict__ bcntB, int e) {
    __shared__ int h[NB];
    const int* dst = (blockIdx.y ? ei1 : ei0) + NEDGES;
    int* bcnt = bcntB + blockIdx.y * NB;
    for (int t = threadIdx.x; t < NB; t += 256) h[t] = 0;
    __syncthreads();
    int base = blockIdx.x * CHUNK;
    int lim = min(base + CHUNK, e);
    for (int i = base + threadIdx.x; i < lim; i += 256) atomicAdd(&h[dst[i] / NPB], 1);
    __syncthreads();
    for (int t = threadIdx.x; t < NB; t += 256)
        if (h[t]) atomicAdd(&bcnt[t], h[t]);
}

__global__ __launch_bounds__(256) void k_bscan(const int* __restrict__ bcntB,
                                               int* __restrict__ boffB,
                                               int* __restrict__ bcurB) {
    __shared__ int s[256];
    int t = threadIdx.x;
    const int* bcnt = bcntB + blockIdx.y * NB;
    int* boff = boffB + blockIdx.y * (NB + 1);
    int* bcur = bcurB + blockIdx.y * NB;
    int v = (t < NB) ? bcnt[t] : 0;
    s[t] = v;
    __syncthreads();
    for (int off = 1; off < 256; off <<= 1) {
        int x = (t >= off) ? s[t - off] : 0;
        __syncthreads();
        s[t] += x;
        __syncthreads();
    }
    if (t < NB) {
        boff[t + 1] = s[t];
        bcur[t] = s[t] - v;  // exclusive
        if (t == 0) boff[0] = 0;
    }
}

// part entry packing: src (16b) | dst_local (8b) | bucket (8b)
__global__ __launch_bounds__(256) void k_part(const int* __restrict__ ei0,
                                              const int* __restrict__ ei1,
                                              int* __restrict__ bcurB,
                                              unsigned int* __restrict__ partB, int e) {
    __shared__ int cnt[NB], boffL[NB], gbase[NB], cur2[NB];
    __shared__ int tmp[256];
    __shared__ unsigned int staged[CHUNK];
    const int* eis = blockIdx.y ? ei1 : ei0;
    int* bcur = bcurB + blockIdx.y * NB;
    unsigned int* part = partB + blockIdx.y * (size_t)NEDGES;
    int t = threadIdx.x;
    for (int i = t; i < NB; i += 256) { cnt[i] = 0; cur2[i] = 0; }
    __syncthreads();
    int base = blockIdx.x * CHUNK;
    int lim = min(base + CHUNK, e);
    int nloc = lim - base;

    int s_[8], b_[8];
    unsigned int pk_[8];
    bool v_[8];
#pragma unroll
    for (int k = 0; k < 8; k++) {
        int i = base + k * 256 + t;
        v_[k] = i < lim;
        pk_[k] = 0; b_[k] = 0;
        if (v_[k]) {
            s_[k] = eis[i];
            int d = eis[NEDGES + i];
            b_[k] = d / NPB;
            int dloc = d - b_[k] * NPB;
            pk_[k] = (unsigned)s_[k] | ((unsigned)dloc << 16) | ((unsigned)b_[k] << 24);
            atomicAdd(&cnt[b_[k]], 1);
        }
    }
    __syncthreads();
    tmp[t] = (t < NB) ? cnt[t] : 0;
    __syncthreads();
    for (int off = 1; off < 256; off <<= 1) {
        int x = (t >= off) ? tmp[t - off] : 0;
        __syncthreads();
        tmp[t] += x;
        __syncthreads();
    }
    if (t < NB) boffL[t] = tmp[t] - cnt[t];
    __syncthreads();
    if (t < NB) {
        int c = cnt[t];
        gbase[t] = c ? atomicAdd(&bcur[t], c) : 0;
    }
    __syncthreads();
#pragma unroll
    for (int k = 0; k < 8; k++) {
        if (v_[k]) {
            int pos = atomicAdd(&cur2[b_[k]], 1);
            staged[boffL[b_[k]] + pos] = pk_[k];
        }
    }
    __syncthreads();
    for (int i = t; i < nloc; i += 256) {
        unsigned int r = staged[i];
        int b = (int)(r >> 24);
        part[gbase[b] + (i - boffL[b])] = r;
    }
}

// per-bucket: histogram -> LDS scan -> row_ptr + self-loop col + place edges
__global__ __launch_bounds__(256) void k_place(const unsigned int* __restrict__ partB,
                                               const int* __restrict__ boffB,
                                               int* __restrict__ rpB, size_t sNp1,
                                               int* __restrict__ colB, size_t sE) {
    __shared__ int h[NPB];
    __shared__ int lds4[4];
    int b = blockIdx.x;
    const int* boff = boffB + blockIdx.y * (NB + 1);
    const unsigned int* part = partB + blockIdx.y * (size_t)NEDGES;
    int* row_ptr = rpB + blockIdx.y * sNp1;
    int* col = colB + blockIdx.y * sE;
    int t = threadIdx.x;
    int n0 = b * NPB;
    if (t < NPB) h[t] = 0;
    __syncthreads();
    int beg = boff[b], end = boff[b + 1];
    for (int i = beg + t; i < end; i += 256) atomicAdd(&h[(part[i] >> 16) & 0xFF], 1);
    __syncthreads();
    int v = (t < NPB) ? h[t] : 0;
    int lane = t & 63, wid = t >> 6;
    int incl = v;
#pragma unroll
    for (int off = 1; off < 64; off <<= 1) {
        int nv = __shfl_up(incl, off);
        if (lane >= off) incl += nv;
    }
    if (lane == 63) lds4[wid] = incl;
    __syncthreads();
    if (t == 0) {
        int s = 0;
#pragma unroll
        for (int j = 0; j < 4; j++) { s += lds4[j]; lds4[j] = s; }
    }
    __syncthreads();
    if (wid > 0) incl += lds4[wid - 1];
    if (t < NPB) {
        int rp_end = beg + n0 + incl + t + 1;   // row_ptr[n0+t+1]
        row_ptr[n0 + t + 1] = rp_end;
        int rp_start = rp_end - v - 1;
        col[rp_start] = n0 + t;                  // self loop at segment head
        h[t] = rp_start + 1;                     // cursor
        if (b == 0 && t == 0) row_ptr[0] = 0;
    }
    __syncthreads();
    for (int i = beg + t; i < end; i += 256) {
        unsigned int r = part[i];
        int p = atomicAdd(&h[(r >> 16) & 0xFF], 1);
        col[p] = (int)(r & 0xFFFF);
    }
}

// ================= MFMA GEMM (conv layers): [M,128] @ Wt[128][128] -> [M,128] bf16 =================

template <bool AF32>
__global__ __launch_bounds__(256) void k_gemm_conv(const float* __restrict__ x0,
                                                   const float* __restrict__ x1,
                                                   const __bf16* __restrict__ Ab, size_t As_,
                                                   const __bf16* __restrict__ Wt,
                                                   const float* __restrict__ Was,
                                                   const float* __restrict__ Wad,
                                                   float* __restrict__ asB, float* __restrict__ adB,
                                                   size_t aS,
                                                   __bf16* __restrict__ OutB, size_t Os_, int M) {
    constexpr int BN = 128;
    __shared__ __align__(16) unsigned short As[64][136];
    __shared__ __align__(16) unsigned short Bs[BN][136];
    const int tid = threadIdx.x;
    const int lane = tid & 63, w = tid >> 6;
    const int row0 = blockIdx.x * 64;
    __bf16* Out = OutB + blockIdx.y * Os_;

#pragma unroll
    for (int t = 0; t < 4; t++) {
        int ch = t * 256 + tid;
        int r = ch >> 4, cx = ch & 15;
        int grow = row0 + r;
        bf16x8 v = {};
        if (grow < M) {
            if (AF32) {
                const float* Ap = (blockIdx.y ? x1 : x0) + (size_t)grow * 128 + cx * 8;
                float4 f0 = *reinterpret_cast<const float4*>(Ap);
                float4 f1 = *reinterpret_cast<const float4*>(Ap + 4);
                v[0] = (__bf16)f0.x; v[1] = (__bf16)f0.y; v[2] = (__bf16)f0.z; v[3] = (__bf16)f0.w;
                v[4] = (__bf16)f1.x; v[5] = (__bf16)f1.y; v[6] = (__bf16)f1.z; v[7] = (__bf16)f1.w;
            } else {
                v = *reinterpret_cast<const bf16x8*>(Ab + blockIdx.y * As_ + (size_t)grow * 128 + cx * 8);
            }
        }
        *reinterpret_cast<bf16x8*>(&As[r][cx * 8]) = v;
    }
#pragma unroll
    for (int t = 0; t < 8; t++) {
        int ch = t * 256 + tid;
        int r = ch >> 4, cx = ch & 15;
        bf16x8 v = *reinterpret_cast<const bf16x8*>(Wt + (size_t)r * 128 + cx * 8);
        *reinterpret_cast<bf16x8*>(&Bs[r][cx * 8]) = v;
    }
    __syncthreads();

    {   // fused alpha: per row dot with Wa vectors
        int row = tid >> 2, seg = tid & 3;
        float ss = 0.f, sd = 0.f;
#pragma unroll
        for (int k = 0; k < 32; k++) {
            int kk = seg * 32 + k;
            float a = __int_as_float(((unsigned)As[row][kk]) << 16);
            ss += a * Was[kk];
            sd += a * Wad[kk];
        }
        ss += __shfl_xor(ss, 1); ss += __shfl_xor(ss, 2);
        sd += __shfl_xor(sd, 1); sd += __shfl_xor(sd, 2);
        if (seg == 0) {
            int grow = row0 + row;
            if (grow < M) {
                (asB + blockIdx.y * aS)[grow] = ss;
                (adB + blockIdx.y * aS)[grow] = sd;
            }
        }
    }

    const int wr0 = (w >> 1) * 32;
    const int wc0 = (w & 1) * 64;
    f32x4 acc[2][4] = {};

#pragma unroll
    for (int ks = 0; ks < 4; ks++) {
        const int koff = ks * 32 + (lane >> 4) * 8;
        bf16x8 af[2], bfr[4];
#pragma unroll
        for (int mf = 0; mf < 2; mf++)
            af[mf] = *reinterpret_cast<const bf16x8*>(&As[wr0 + mf * 16 + (lane & 15)][koff]);
#pragma unroll
        for (int nf = 0; nf < 4; nf++)
            bfr[nf] = *reinterpret_cast<const bf16x8*>(&Bs[wc0 + nf * 16 + (lane & 15)][koff]);
#pragma unroll
        for (int mf = 0; mf < 2; mf++)
#pragma unroll
            for (int nf = 0; nf < 4; nf++)
                acc[mf][nf] = __builtin_amdgcn_mfma_f32_16x16x32_bf16(af[mf], bfr[nf], acc[mf][nf], 0, 0, 0);
    }

#pragma unroll
    for (int mf = 0; mf < 2; mf++) {
#pragma unroll
        for (int r = 0; r < 4; r++) {
            int row = row0 + wr0 + mf * 16 + (lane >> 4) * 4 + r;
            if (row >= M) continue;
#pragma unroll
            for (int nf = 0; nf < 4; nf++) {
                int colc = wc0 + nf * 16 + (lane & 15);
                Out[(size_t)row * BN + colc] = (__bf16)acc[mf][nf][r];
            }
        }
    }
}

// ================= fused segment-softmax + aggregate + bias + ELU =================
// 16-lane group per node; batched gathers (8 outstanding) for latency hiding.

__device__ __forceinline__ void gather16(const char* __restrict__ hbase, int foff, int base,
                                         int c, float wn, int cnt, float (&acc)[8]) {
#pragma unroll
    for (int j0 = 0; j0 < 16; j0 += 8) {
        if (j0 < cnt) {
            bf16x8 hv[8];
            float ww[8];
#pragma unroll
            for (int j = 0; j < 8; j++) {
                int cj = __shfl(c, base + j0 + j);
                float wj = __shfl(wn, base + j0 + j);
                bool lv = (j0 + j) < cnt;
                ww[j] = lv ? wj : 0.f;
                const char* ap = hbase + ((size_t)(unsigned)cj << 8) + foff;
                hv[j] = lv ? *reinterpret_cast<const bf16x8*>(ap) : bf16x8{};
            }
#pragma unroll
            for (int j = 0; j < 8; j++)
#pragma unroll
                for (int q = 0; q < 8; q++) acc[q] += ww[j] * (float)hv[j][q];
        }
    }
}

__global__ __launch_bounds__(256) void k_gat_agg(const __bf16* __restrict__ hB, size_t hS,
                                                 const float* __restrict__ asB,
                                                 const float* __restrict__ adB, size_t aS,
                                                 const int* __restrict__ rpB, size_t sNp1,
                                                 const int* __restrict__ colB, size_t sE,
                                                 const float* __restrict__ bias,
                                                 __bf16* __restrict__ outB, size_t oS, int n) {
    int grp = threadIdx.x >> 4;
    int node = blockIdx.x * 16 + grp;
    int l = threadIdx.x & 15;
    if (node >= n) return;
    const float* alpha_s = asB + blockIdx.y * aS;
    const int* row_ptr = rpB + blockIdx.y * sNp1;
    const int* col = colB + blockIdx.y * sE;
    const char* hbase = (const char*)(hB + blockIdx.y * hS);
    float ad = (adB + blockIdx.y * aS)[node];
    int beg = row_ptr[node], end = row_ptr[node + 1];
    int deg = end - beg;
    int foff = l * 16;
    int base = (threadIdx.x & 63) & 48;  // group base lane within wave

    float acc[8] = {0.f, 0.f, 0.f, 0.f, 0.f, 0.f, 0.f, 0.f};

    if (deg <= 16) {
        bool v = l < deg;
        int c = 0;
        float e = -1e30f;
        if (v) {
            c = col[beg + l];
            float t = alpha_s[c] + ad;
            e = (t > 0.f) ? t : 0.2f * t;
        }
        float m = e;
#pragma unroll
        for (int off = 8; off; off >>= 1) m = fmaxf(m, __shfl_xor(m, off));
        float ex = v ? __expf(e - m) : 0.f;
        float den = ex;
#pragma unroll
        for (int off = 8; off; off >>= 1) den += __shfl_xor(den, off);
        float wn = ex / den;
        gather16(hbase, foff, base, c, wn, deg, acc);
    } else {
        float m = -1e30f;
        for (int i = beg + l; i < end; i += 16) {
            float t = alpha_s[col[i]] + ad;
            t = (t > 0.f) ? t : 0.2f * t;
            m = fmaxf(m, t);
        }
#pragma unroll
        for (int off = 8; off; off >>= 1) m = fmaxf(m, __shfl_xor(m, off));
        float den = 0.f;
        for (int i = beg + l; i < end; i += 16) {
            float t = alpha_s[col[i]] + ad;
            t = (t > 0.f) ? t : 0.2f * t;
            den += __expf(t - m);
        }
#pragma unroll
        for (int off = 8; off; off >>= 1) den += __shfl_xor(den, off);
        float rinv = 1.f / den;
        for (int i0 = beg; i0 < end; i0 += 16) {
            int idx = i0 + l;
            bool lv = idx < end;
            int cb = lv ? col[idx] : 0;
            float wv = 0.f;
            if (lv) {
                float t = alpha_s[cb] + ad;
                t = (t > 0.f) ? t : 0.2f * t;
                wv = __expf(t - m) * rinv;
            }
            int cnt = min(end - i0, 16);
            gather16(hbase, foff, base, cb, wv, cnt, acc);
        }
    }

    // epilogue: lane l owns features l*8 .. l*8+7
    float4 b0 = *reinterpret_cast<const float4*>(bias + l * 8);
    float4 b1 = *reinterpret_cast<const float4*>(bias + l * 8 + 4);
    float bb[8] = {b0.x, b0.y, b0.z, b0.w, b1.x, b1.y, b1.z, b1.w};
    bf16x8 o;
#pragma unroll
    for (int q = 0; q < 8; q++) {
        float x = acc[q] + bb[q];
        x = (x > 0.f) ? x : __expf(x) - 1.f;
        o[q] = (__bf16)x;
    }
    *reinterpret_cast<bf16x8*>((char*)(outB + blockIdx.y * oS) + ((size_t)(unsigned)node << 8) + foff) = o;
}

// ================= fused MLP (relu GEMM -> GEMM) + segment pool =================

__global__ __launch_bounds__(256) void k_mlp_pool(const __bf16* __restrict__ AbB, size_t As_,
                                                  const __bf16* __restrict__ Wt1,
                                                  const __bf16* __restrict__ Wt2,
                                                  const float* __restrict__ b1,
                                                  const float* __restrict__ b2,
                                                  const int* __restrict__ bat0,
                                                  const int* __restrict__ bat1,
                                                  float* __restrict__ pB, size_t pS, int M) {
    __shared__ __align__(16) unsigned short As[64][136];
    __shared__ __align__(16) unsigned short Bs[128][136];
    const int tid = threadIdx.x;
    const int lane = tid & 63, w = tid >> 6;
    const int row0 = blockIdx.x * 64;
    const __bf16* Ab = AbB + blockIdx.y * As_;
    const int* batch = blockIdx.y ? bat1 : bat0;
    float* p = pB + blockIdx.y * pS;

#pragma unroll
    for (int t = 0; t < 4; t++) {
        int ch = t * 256 + tid;
        int r = ch >> 4, cx = ch & 15;
        int grow = row0 + r;
        bf16x8 v = {};
        if (grow < M) v = *reinterpret_cast<const bf16x8*>(Ab + (size_t)grow * 128 + cx * 8);
        *reinterpret_cast<bf16x8*>(&As[r][cx * 8]) = v;
    }
#pragma unroll
    for (int t = 0; t < 8; t++) {
        int ch = t * 256 + tid;
        int r = ch >> 4, cx = ch & 15;
        bf16x8 v = *reinterpret_cast<const bf16x8*>(Wt1 + (size_t)r * 128 + cx * 8);
        *reinterpret_cast<bf16x8*>(&Bs[r][cx * 8]) = v;
    }
    __syncthreads();

    {
        const int wr0 = (w >> 1) * 32;
        const int wc0 = (w & 1) * 64;
        f32x4 acc[2][4] = {};
#pragma unroll
        for (int ks = 0; ks < 4; ks++) {
            const int koff = ks * 32 + (lane >> 4) * 8;
            bf16x8 af[2], bfr[4];
#pragma unroll
            for (int mf = 0; mf < 2; mf++)
                af[mf] = *reinterpret_cast<const bf16x8*>(&As[wr0 + mf * 16 + (lane & 15)][koff]);
#pragma unroll
            for (int nf = 0; nf < 4; nf++)
                bfr[nf] = *reinterpret_cast<const bf16x8*>(&Bs[wc0 + nf * 16 + (lane & 15)][koff]);
#pragma unroll
            for (int mf = 0; mf < 2; mf++)
#pragma unroll
                for (int nf = 0; nf < 4; nf++)
                    acc[mf][nf] = __builtin_amdgcn_mfma_f32_16x16x32_bf16(af[mf], bfr[nf], acc[mf][nf], 0, 0, 0);
        }
        __syncthreads();
#pragma unroll
        for (int mf = 0; mf < 2; mf++)
#pragma unroll
            for (int r = 0; r < 4; r++) {
                int row = wr0 + mf * 16 + (lane >> 4) * 4 + r;
#pragma unroll
                for (int nf = 0; nf < 4; nf++) {
                    int colc = wc0 + nf * 16 + (lane & 15);
                    float v = fmaxf(acc[mf][nf][r] + b1[colc], 0.f);
                    As[row][colc] = __builtin_bit_cast(unsigned short, (__bf16)v);
                }
            }
#pragma unroll
        for (int t = 0; t < 4; t++) {
            int ch = t * 256 + tid;
            int r = ch >> 4, cx = ch & 15;
            bf16x8 v = *reinterpret_cast<const bf16x8*>(Wt2 + (size_t)r * 128 + cx * 8);
            *reinterpret_cast<bf16x8*>(&Bs[r][cx * 8]) = v;
        }
        __syncthreads();
    }

    const int wr2 = w * 16;
    f32x4 acc2[4] = {};
#pragma unroll
    for (int ks = 0; ks < 4; ks++) {
        const int koff = ks * 32 + (lane >> 4) * 8;
        bf16x8 a2 = *reinterpret_cast<const bf16x8*>(&As[wr2 + (lane & 15)][koff]);
#pragma unroll
        for (int nf = 0; nf < 4; nf++) {
            bf16x8 bf2 = *reinterpret_cast<const bf16x8*>(&Bs[nf * 16 + (lane & 15)][koff]);
            acc2[nf] = __builtin_amdgcn_mfma_f32_16x16x32_bf16(a2, bf2, acc2[nf], 0, 0, 0);
        }
    }

    int q = lane >> 4, c = lane & 15;
    bool full = (row0 + 63) < M;
    int g0 = batch[min(row0, M - 1)];
    int g1 = batch[min(row0 + 63, M - 1)];
    if (full && g0 == g1) {
        float s0 = acc2[0][0] + acc2[0][1] + acc2[0][2] + acc2[0][3];
        float s1 = acc2[1][0] + acc2[1][1] + acc2[1][2] + acc2[1][3];
        float s2 = acc2[2][0] + acc2[2][1] + acc2[2][2] + acc2[2][3];
        float s3 = acc2[3][0] + acc2[3][1] + acc2[3][2] + acc2[3][3];
        s0 += __shfl_xor(s0, 16); s0 += __shfl_xor(s0, 32);
        s1 += __shfl_xor(s1, 16); s1 += __shfl_xor(s1, 32);
        s2 += __shfl_xor(s2, 16); s2 += __shfl_xor(s2, 32);
        s3 += __shfl_xor(s3, 16); s3 += __shfl_xor(s3, 32);
        float v = (q & 2) ? ((q & 1) ? s3 : s2) : ((q & 1) ? s1 : s0);
        v += 16.f * b2[q * 16 + c];
        atomicAdd(&p[g0 * CDIM + q * 16 + c], v);
    } else {
        float b2v[4];
#pragma unroll
        for (int nf = 0; nf < 4; nf++) b2v[nf] = b2[nf * 16 + c];
#pragma unroll
        for (int r = 0; r < 4; r++) {
            int row = row0 + wr2 + q * 4 + r;
            if (row >= M) continue;
            int g = batch[row];
#pragma unroll
            for (int nf = 0; nf < 4; nf++)
                atomicAdd(&p[g * CDIM + nf * 16 + c], acc2[nf][r] + b2v[nf]);
        }
    }
}

// ================= final p1^T @ p2 =================

__global__ __launch_bounds__(64) void k_final(const float* __restrict__ p, float* __restrict__ out) {
    int i = blockIdx.x;
    int j = threadIdx.x;
    const float* p1 = p;
    const float* p2 = p + GDIM * CDIM;
    float s = 0.f;
    for (int g = 0; g < GDIM; ++g) s += p1[g * CDIM + i] * p2[g * CDIM + j];
    out[i * CDIM + j] = s;
}

// ================= host side =================

static inline size_t align_up(size_t x, size_t a) { return (x + a - 1) & ~(a - 1); }

struct Ws {
    __bf16 *Hb, *Yb;
    __bf16 *WtC, *Wt1, *Wt2;
    float *alpha_s, *alpha_d, *Wa, *p;
    int *row_ptr, *col;
    int *bcnt, *boff, *bcur;
    unsigned int* part;
    size_t sNH, sN, sNp1, sE;
    size_t need;
};

static Ws carve(void* ws, bool combined) {
    char* p = (char*)ws;
    size_t off = 0;
    Ws w;
    int nb = combined ? 2 : 1;
    auto take = [&](size_t bytes) {
        char* r = p + off;
        off = align_up(off + bytes, 256);
        return r;
    };
    w.Hb = (__bf16*)take((size_t)nb * NNODES * HDIM * 2);
    w.Yb = (__bf16*)take((size_t)nb * NNODES * HDIM * 2);
    w.alpha_s = (float*)take((size_t)nb * NNODES * 4);
    w.alpha_d = (float*)take((size_t)nb * NNODES * 4);
    w.col = (int*)take((size_t)nb * NTOT * 4);
    w.part = (unsigned int*)take((size_t)nb * NEDGES * 4);
    w.row_ptr = (int*)take((size_t)nb * (NNODES + 1) * 4);
    w.bcnt = (int*)take((size_t)2 * NB * 4);
    w.boff = (int*)take((size_t)2 * (NB + 1) * 4);
    w.bcur = (int*)take((size_t)2 * NB * 4);
    w.WtC = (__bf16*)take((size_t)2 * HDIM * HDIM * 2);
    w.Wt1 = (__bf16*)take((size_t)HDIM * HDIM * 2);
    w.Wt2 = (__bf16*)take((size_t)HDIM * CDIM * 2);
    w.Wa = (float*)take((size_t)512 * 4);
    w.p = (float*)take((size_t)2 * GDIM * CDIM * 4);
    w.need = off;
    size_t s = combined ? 1 : 0;
    w.sNH = s * (size_t)NNODES * HDIM;
    w.sN = s * (size_t)NNODES;
    w.sNp1 = s * (size_t)(NNODES + 1);
    w.sE = s * (size_t)NTOT;
    return w;
}

static void pipeline(const Ws& w, const float* xA, const float* xB,
                     const int* eiA, const int* eiB,
                     const int* batA, const int* batB,
                     const float* conv_b, const float* b1, const float* b2,
                     float* pbase, size_t pstride, int yc, hipStream_t stream) {
    const int N = NNODES, E = NEDGES;
    dim3 gC(NCHB, yc), gB(NB, yc), g1(1, yc);
    dim3 gW((N + 15) / 16, yc);
    dim3 gG((N + 63) / 64, yc);

    // ---- CSR build (bucketed, write-local) ----
    hipMemsetAsync(w.bcnt, 0, (size_t)yc * NB * 4, stream);
    k_bhist<<<gC, 256, 0, stream>>>(eiA, eiB, w.bcnt, E);
    k_bscan<<<g1, 256, 0, stream>>>(w.bcnt, w.boff, w.bcur);
    k_part<<<gC, 256, 0, stream>>>(eiA, eiB, w.bcur, w.part, E);
    k_place<<<gB, 256, 0, stream>>>(w.part, w.boff, w.row_ptr, w.sNp1, w.col, w.sE);

    // ---- conv layer 0 ----
    k_gemm_conv<true><<<gG, 256, 0, stream>>>(
        xA, xB, nullptr, 0, w.WtC, w.Wa, w.Wa + 128,
        w.alpha_s, w.alpha_d, w.sN, w.Hb, w.sNH, N);
    k_gat_agg<<<gW, 256, 0, stream>>>(w.Hb, w.sNH, w.alpha_s, w.alpha_d, w.sN,
                                      w.row_ptr, w.sNp1, w.col, w.sE, conv_b, w.Yb, w.sNH, N);
    // ---- conv layer 1 ----
    k_gemm_conv<false><<<gG, 256, 0, stream>>>(
        nullptr, nullptr, w.Yb, w.sNH, w.WtC + HDIM * HDIM, w.Wa + 256, w.Wa + 384,
        w.alpha_s, w.alpha_d, w.sN, w.Hb, w.sNH, N);
    k_gat_agg<<<gW, 256, 0, stream>>>(w.Hb, w.sNH, w.alpha_s, w.alpha_d, w.sN,
                                      w.row_ptr, w.sNp1, w.col, w.sE, conv_b + HDIM, w.Yb, w.sNH, N);
    // ---- fused MLP + pool ----
    k_mlp_pool<<<gG, 256, 0, stream>>>(w.Yb, w.sNH, w.Wt1, w.Wt2, b1, b2,
                                       batA, batB, pbase, pstride, N);
}

extern "C" void kernel_launch(void* const* d_in, const int* in_sizes, int n_in, void* d_out,
                              int out_size, void* d_ws, size_t ws_size, hipStream_t stream) {
    const float* x1      = (const float*)d_in[0];
    const float* x2      = (const float*)d_in[1];
    const float* convW   = (const float*)d_in[2];
    const float* att_src = (const float*)d_in[3];
    const float* att_dst = (const float*)d_in[4];
    const float* conv_b  = (const float*)d_in[5];
    const float* mlp_w1  = (const float*)d_in[6];
    const float* mlp_b1  = (const float*)d_in[7];
    const float* mlp_w2  = (const float*)d_in[8];
    const float* mlp_b2  = (const float*)d_in[9];
    const int* ei1       = (const int*)d_in[10];
    const int* batch1    = (const int*)d_in[11];
    const int* ei2       = (const int*)d_in[12];
    const int* batch2    = (const int*)d_in[13];
    float* out = (float*)d_out;

    Ws wc = carve(d_ws, true);
    bool combined = ws_size >= wc.need;
    Ws w = combined ? wc : carve(d_ws, false);

    k_setup<<<226, 256, 0, stream>>>(convW, mlp_w1, mlp_w2, att_src, att_dst,
                                     w.WtC, w.Wt1, w.Wt2, w.Wa, w.p);

    if (combined) {
        pipeline(w, x1, x2, ei1, ei2, batch1, batch2, conv_b,
                 mlp_b1, mlp_b2, w.p, (size_t)GDIM * CDIM, 2, stream);
    } else {
        pipeline(w, x1, x1, ei1, ei1, batch1, batch1, conv_b,
                 mlp_b1, mlp_b2, w.p, 0, 1, stream);
        pipeline(w, x2, x2, ei2, ei2, batch2, batch2, conv_b,
                 mlp_b1, mlp_b2, w.p + GDIM * CDIM, 0, 1, stream);
    }

    k_final<<<CDIM, 64, 0, stream>>>(w.p, out);
}

// Round 11
// 346.431 us; speedup vs baseline: 1.0133x; 1.0133x over previous
//
#include <hip/hip_runtime.h>
#include <hip/hip_cooperative_groups.h>
#include <cstdint>
#include <cstddef>

namespace cg = cooperative_groups;

#define NNODES 50000
#define NEDGES 500000
#define NTOT (NEDGES + NNODES)
#define HDIM 128
#define CDIM 64
#define GDIM 64
#define NB 250      // buckets
#define NPB 200     // nodes per bucket
#define CHUNK 2048  // edges per partition block
#define NCHB ((NEDGES + CHUNK - 1) / CHUNK)   // 245
#define SNH ((size_t)NNODES * HDIM)
#define SN ((size_t)NNODES)
#define SNP1 ((size_t)(NNODES + 1))
#define SE ((size_t)NTOT)
#define GEMM_TILES ((NNODES + 63) / 64)       // 782
#define AGG_UNITS (NNODES / 16)               // 3125

typedef __bf16 bf16x8 __attribute__((ext_vector_type(8)));
typedef __bf16 bf16x2 __attribute__((ext_vector_type(2)));
typedef float f32x4 __attribute__((ext_vector_type(4)));
typedef unsigned short ushort_t;

struct MegaArgs {
    const float *x0, *x1, *convW, *att_s, *att_d, *conv_b, *w1, *b1, *w2, *b2;
    const int *ei0, *ei1, *bat0, *bat1;
    __bf16 *Hb, *Yb, *WtC, *Wt1, *Wt2;
    float *alpha_s, *alpha_d, *Wa, *p;
    int *row_ptr, *col, *bcnt, *boff, *bcur;
    unsigned int* part;
    float* out;
    int nblk;
};

// ================= device phase bodies =================

__device__ void d_setup(int b, int tid, const MegaArgs& A) {
    if (b < 128) {
        int i = b * 256 + tid;
        int mat = i >> 14, rem = i & 16383;
        int k = rem >> 7, n = rem & 127;
        A.WtC[mat * 16384 + n * 128 + k] = (__bf16)A.convW[i];
    } else if (b < 192) {
        int i = (b - 128) * 256 + tid;
        int k = i >> 7, n = i & 127;
        A.Wt1[n * 128 + k] = (__bf16)A.w1[i];
    } else if (b < 224) {
        int i = (b - 192) * 256 + tid;
        int k = i >> 6, n = i & 63;
        A.Wt2[n * 128 + k] = (__bf16)A.w2[i];
    } else if (b == 224) {
        for (int o = tid; o < 512; o += 256) {
            int l = o >> 8, r = o & 255;
            int type = r >> 7, k = r & 127;
            const float* a = (type ? A.att_d : A.att_s) + l * 128;
            const float* Wrow = A.convW + l * 16384 + k * 128;
            float s = 0.f;
            for (int j = 0; j < 128; j++) s += Wrow[j] * a[j];
            A.Wa[o] = s;
        }
    } else {
        for (int i = tid; i < 2 * GDIM * CDIM; i += 256) A.p[i] = 0.f;
    }
}

__device__ void d_bhist(int u, int br, int tid, const MegaArgs& A, char* smem) {
    int* h = (int*)smem;
    const int* dst = (br ? A.ei1 : A.ei0) + NEDGES;
    int* bcnt = A.bcnt + br * NB;
    for (int t = tid; t < NB; t += 256) h[t] = 0;
    __syncthreads();
    int base = u * CHUNK;
    int lim = min(base + CHUNK, NEDGES);
    for (int i = base + tid; i < lim; i += 256) atomicAdd(&h[dst[i] / NPB], 1);
    __syncthreads();
    for (int t = tid; t < NB; t += 256)
        if (h[t]) atomicAdd(&bcnt[t], h[t]);
    __syncthreads();
}

__device__ void d_bscan(int br, int tid, const MegaArgs& A, char* smem) {
    int* s = (int*)smem;
    const int* bcnt = A.bcnt + br * NB;
    int* boff = A.boff + br * (NB + 1);
    int* bcur = A.bcur + br * NB;
    int t = tid;
    int v = (t < NB) ? bcnt[t] : 0;
    s[t] = v;
    __syncthreads();
    for (int off = 1; off < 256; off <<= 1) {
        int x = (t >= off) ? s[t - off] : 0;
        __syncthreads();
        s[t] += x;
        __syncthreads();
    }
    if (t < NB) {
        boff[t + 1] = s[t];
        bcur[t] = s[t] - v;
        if (t == 0) boff[0] = 0;
    }
    __syncthreads();
}

__device__ void d_part(int u, int br, int tid, const MegaArgs& A, char* smem) {
    int* cnt = (int*)smem;
    int* boffL = cnt + NB;
    int* gbase = boffL + NB;
    int* cur2 = gbase + NB;
    int* tmp = cur2 + NB;
    unsigned int* staged = (unsigned int*)(tmp + 256);
    const int* eis = br ? A.ei1 : A.ei0;
    int* bcur = A.bcur + br * NB;
    unsigned int* part = A.part + br * (size_t)NEDGES;
    int t = tid;
    for (int i = t; i < NB; i += 256) { cnt[i] = 0; cur2[i] = 0; }
    __syncthreads();
    int base = u * CHUNK;
    int lim = min(base + CHUNK, NEDGES);
    int nloc = lim - base;

    int b_[8];
    unsigned int pk_[8];
    bool v_[8];
#pragma unroll
    for (int k = 0; k < 8; k++) {
        int i = base + k * 256 + t;
        v_[k] = i < lim;
        pk_[k] = 0; b_[k] = 0;
        if (v_[k]) {
            int s = eis[i];
            int d = eis[NEDGES + i];
            b_[k] = d / NPB;
            int dloc = d - b_[k] * NPB;
            pk_[k] = (unsigned)s | ((unsigned)dloc << 16) | ((unsigned)b_[k] << 24);
            atomicAdd(&cnt[b_[k]], 1);
        }
    }
    __syncthreads();
    tmp[t] = (t < NB) ? cnt[t] : 0;
    __syncthreads();
    for (int off = 1; off < 256; off <<= 1) {
        int x = (t >= off) ? tmp[t - off] : 0;
        __syncthreads();
        tmp[t] += x;
        __syncthreads();
    }
    if (t < NB) boffL[t] = tmp[t] - cnt[t];
    __syncthreads();
    if (t < NB) {
        int c = cnt[t];
        gbase[t] = c ? atomicAdd(&bcur[t], c) : 0;
    }
    __syncthreads();
#pragma unroll
    for (int k = 0; k < 8; k++) {
        if (v_[k]) {
            int pos = atomicAdd(&cur2[b_[k]], 1);
            staged[boffL[b_[k]] + pos] = pk_[k];
        }
    }
    __syncthreads();
    for (int i = t; i < nloc; i += 256) {
        unsigned int r = staged[i];
        int b = (int)(r >> 24);
        part[gbase[b] + (i - boffL[b])] = r;
    }
    __syncthreads();
}

__device__ void d_place(int b, int br, int tid, const MegaArgs& A, char* smem) {
    int* h = (int*)smem;
    int* lds4 = h + NPB;
    const int* boff = A.boff + br * (NB + 1);
    const unsigned int* part = A.part + br * (size_t)NEDGES;
    int* row_ptr = A.row_ptr + br * SNP1;
    int* col = A.col + br * SE;
    int t = tid;
    int n0 = b * NPB;
    if (t < NPB) h[t] = 0;
    __syncthreads();
    int beg = boff[b], end = boff[b + 1];
    for (int i = beg + t; i < end; i += 256) atomicAdd(&h[(part[i] >> 16) & 0xFF], 1);
    __syncthreads();
    int v = (t < NPB) ? h[t] : 0;
    int lane = t & 63, wid = t >> 6;
    int incl = v;
#pragma unroll
    for (int off = 1; off < 64; off <<= 1) {
        int nv = __shfl_up(incl, off);
        if (lane >= off) incl += nv;
    }
    if (lane == 63) lds4[wid] = incl;
    __syncthreads();
    if (t == 0) {
        int s = 0;
#pragma unroll
        for (int j = 0; j < 4; j++) { s += lds4[j]; lds4[j] = s; }
    }
    __syncthreads();
    if (wid > 0) incl += lds4[wid - 1];
    if (t < NPB) {
        int rp_end = beg + n0 + incl + t + 1;
        row_ptr[n0 + t + 1] = rp_end;
        int rp_start = rp_end - v - 1;
        col[rp_start] = n0 + t;
        h[t] = rp_start + 1;
        if (b == 0 && t == 0) row_ptr[0] = 0;
    }
    __syncthreads();
    for (int i = beg + t; i < end; i += 256) {
        unsigned int r = part[i];
        int p = atomicAdd(&h[(r >> 16) & 0xFF], 1);
        col[p] = (int)(r & 0xFFFF);
    }
    __syncthreads();
}

template <bool AF32>
__device__ void d_gemm_tile(int u, int br, int tid, const MegaArgs& A, char* smem) {
    ushort_t (*As)[136] = (ushort_t(*)[136])smem;
    ushort_t (*Bs)[136] = (ushort_t(*)[136])(smem + 64 * 136 * 2);
    const int lane = tid & 63, w = tid >> 6;
    const int row0 = u * 64;
    const int M = NNODES;
    const __bf16* Wt = AF32 ? A.WtC : (A.WtC + HDIM * HDIM);
    const float* Was = AF32 ? A.Wa : (A.Wa + 256);
    const float* Wad = AF32 ? (A.Wa + 128) : (A.Wa + 384);
    const __bf16* Ab = A.Yb + br * SNH;
    __bf16* Out = A.Hb + br * SNH;
    float* asB = A.alpha_s + br * SN;
    float* adB = A.alpha_d + br * SN;

#pragma unroll
    for (int t = 0; t < 4; t++) {
        int ch = t * 256 + tid;
        int r = ch >> 4, cx = ch & 15;
        int grow = row0 + r;
        bf16x8 v = {};
        if (grow < M) {
            if (AF32) {
                const float* Ap = (br ? A.x1 : A.x0) + (size_t)grow * 128 + cx * 8;
                float4 f0 = *reinterpret_cast<const float4*>(Ap);
                float4 f1 = *reinterpret_cast<const float4*>(Ap + 4);
                v[0] = (__bf16)f0.x; v[1] = (__bf16)f0.y; v[2] = (__bf16)f0.z; v[3] = (__bf16)f0.w;
                v[4] = (__bf16)f1.x; v[5] = (__bf16)f1.y; v[6] = (__bf16)f1.z; v[7] = (__bf16)f1.w;
            } else {
                v = *reinterpret_cast<const bf16x8*>(Ab + (size_t)grow * 128 + cx * 8);
            }
        }
        *reinterpret_cast<bf16x8*>(&As[r][cx * 8]) = v;
    }
#pragma unroll
    for (int t = 0; t < 8; t++) {
        int ch = t * 256 + tid;
        int r = ch >> 4, cx = ch & 15;
        bf16x8 v = *reinterpret_cast<const bf16x8*>(Wt + (size_t)r * 128 + cx * 8);
        *reinterpret_cast<bf16x8*>(&Bs[r][cx * 8]) = v;
    }
    __syncthreads();

    {   // fused alpha
        int row = tid >> 2, seg = tid & 3;
        float ss = 0.f, sd = 0.f;
#pragma unroll
        for (int k = 0; k < 32; k++) {
            int kk = seg * 32 + k;
            float a = __int_as_float(((unsigned)As[row][kk]) << 16);
            ss += a * Was[kk];
            sd += a * Wad[kk];
        }
        ss += __shfl_xor(ss, 1); ss += __shfl_xor(ss, 2);
        sd += __shfl_xor(sd, 1); sd += __shfl_xor(sd, 2);
        if (seg == 0) {
            int grow = row0 + row;
            if (grow < M) { asB[grow] = ss; adB[grow] = sd; }
        }
    }

    const int wr0 = (w >> 1) * 32;
    const int wc0 = (w & 1) * 64;
    f32x4 acc[2][4] = {};
#pragma unroll
    for (int ks = 0; ks < 4; ks++) {
        const int koff = ks * 32 + (lane >> 4) * 8;
        bf16x8 af[2], bfr[4];
#pragma unroll
        for (int mf = 0; mf < 2; mf++)
            af[mf] = *reinterpret_cast<const bf16x8*>(&As[wr0 + mf * 16 + (lane & 15)][koff]);
#pragma unroll
        for (int nf = 0; nf < 4; nf++)
            bfr[nf] = *reinterpret_cast<const bf16x8*>(&Bs[wc0 + nf * 16 + (lane & 15)][koff]);
#pragma unroll
        for (int mf = 0; mf < 2; mf++)
#pragma unroll
            for (int nf = 0; nf < 4; nf++)
                acc[mf][nf] = __builtin_amdgcn_mfma_f32_16x16x32_bf16(af[mf], bfr[nf], acc[mf][nf], 0, 0, 0);
    }
#pragma unroll
    for (int mf = 0; mf < 2; mf++) {
#pragma unroll
        for (int r = 0; r < 4; r++) {
            int row = row0 + wr0 + mf * 16 + (lane >> 4) * 4 + r;
            if (row >= M) continue;
#pragma unroll
            for (int nf = 0; nf < 4; nf++) {
                int colc = wc0 + nf * 16 + (lane & 15);
                Out[(size_t)row * 128 + colc] = (__bf16)acc[mf][nf][r];
            }
        }
    }
    __syncthreads();
}

__device__ void d_agg(int u, int br, int layer, int tid, const MegaArgs& A) {
    int grp = tid >> 4;
    int node = u * 16 + grp;
    int l = tid & 15;
    if (node >= NNODES) return;
    const float* alpha_s = A.alpha_s + br * SN;
    const int* row_ptr = A.row_ptr + br * SNP1;
    const int* col = A.col + br * SE;
    const char* hbase = (const char*)(A.Hb + br * SNH);
    const float* bias = A.conv_b + layer * HDIM;
    float ad = (A.alpha_d + br * SN)[node];
    int beg = row_ptr[node], end = row_ptr[node + 1];
    int deg = end - beg;
    int foff = l * 16;

    float acc[8] = {0.f, 0.f, 0.f, 0.f, 0.f, 0.f, 0.f, 0.f};

    if (deg <= 16) {
        bool v = l < deg;
        int c = 0;
        float e = -1e30f;
        if (v) {
            c = col[beg + l];
            float t = alpha_s[c] + ad;
            e = (t > 0.f) ? t : 0.2f * t;
        }
        float m = e;
#pragma unroll
        for (int off = 8; off; off >>= 1) m = fmaxf(m, __shfl_xor(m, off));
        float ex = v ? __expf(e - m) : 0.f;
        float den = ex;
#pragma unroll
        for (int off = 8; off; off >>= 1) den += __shfl_xor(den, off);
        float wn = ex / den;

        int base = (grp << 4) & 63;
        for (int e2 = 0; e2 < deg; e2 += 2) {
            int i1 = base + e2, i2 = base + e2 + 1;
            int s1 = __shfl(c, i1); float w1 = __shfl(wn, i1);
            int s2 = __shfl(c, i2); float w2 = __shfl(wn, i2);
            bool h2v = (e2 + 1) < deg;
            s2 = h2v ? s2 : s1;
            w2 = h2v ? w2 : 0.f;
            bf16x8 h1 = *reinterpret_cast<const bf16x8*>(hbase + ((size_t)(unsigned)s1 << 8) + foff);
            bf16x8 hh2 = *reinterpret_cast<const bf16x8*>(hbase + ((size_t)(unsigned)s2 << 8) + foff);
#pragma unroll
            for (int q = 0; q < 8; q++) acc[q] += w1 * (float)h1[q] + w2 * (float)hh2[q];
        }
    } else {
        float m = -1e30f;
        for (int i = beg + l; i < end; i += 16) {
            float t = alpha_s[col[i]] + ad;
            t = (t > 0.f) ? t : 0.2f * t;
            m = fmaxf(m, t);
        }
#pragma unroll
        for (int off = 8; off; off >>= 1) m = fmaxf(m, __shfl_xor(m, off));
        float den = 0.f;
        for (int i = beg + l; i < end; i += 16) {
            float t = alpha_s[col[i]] + ad;
            t = (t > 0.f) ? t : 0.2f * t;
            den += __expf(t - m);
        }
#pragma unroll
        for (int off = 8; off; off >>= 1) den += __shfl_xor(den, off);
        float rinv = 1.f / den;
        for (int e2 = beg; e2 < end; e2++) {
            int cc = col[e2];
            float t = alpha_s[cc] + ad;
            t = (t > 0.f) ? t : 0.2f * t;
            float wv = __expf(t - m) * rinv;
            bf16x8 hv = *reinterpret_cast<const bf16x8*>(hbase + ((size_t)(unsigned)cc << 8) + foff);
#pragma unroll
            for (int q = 0; q < 8; q++) acc[q] += wv * (float)hv[q];
        }
    }

    float4 b0 = *reinterpret_cast<const float4*>(bias + l * 8);
    float4 b1 = *reinterpret_cast<const float4*>(bias + l * 8 + 4);
    float bb[8] = {b0.x, b0.y, b0.z, b0.w, b1.x, b1.y, b1.z, b1.w};
    bf16x8 o;
#pragma unroll
    for (int q = 0; q < 8; q++) {
        float x = acc[q] + bb[q];
        x = (x > 0.f) ? x : __expf(x) - 1.f;
        o[q] = (__bf16)x;
    }
    *reinterpret_cast<bf16x8*>((char*)(A.Yb + br * SNH) + ((size_t)(unsigned)node << 8) + foff) = o;
}

__device__ void d_mlp(int u, int br, int tid, const MegaArgs& A, char* smem) {
    ushort_t (*As)[136] = (ushort_t(*)[136])smem;
    ushort_t (*Bs)[136] = (ushort_t(*)[136])(smem + 64 * 136 * 2);
    const int lane = tid & 63, w = tid >> 6;
    const int row0 = u * 64;
    const int M = NNODES;
    const __bf16* Ab = A.Yb + br * SNH;
    const int* batch = br ? A.bat1 : A.bat0;
    float* p = A.p + br * (GDIM * CDIM);

#pragma unroll
    for (int t = 0; t < 4; t++) {
        int ch = t * 256 + tid;
        int r = ch >> 4, cx = ch & 15;
        int grow = row0 + r;
        bf16x8 v = {};
        if (grow < M) v = *reinterpret_cast<const bf16x8*>(Ab + (size_t)grow * 128 + cx * 8);
        *reinterpret_cast<bf16x8*>(&As[r][cx * 8]) = v;
    }
#pragma unroll
    for (int t = 0; t < 8; t++) {
        int ch = t * 256 + tid;
        int r = ch >> 4, cx = ch & 15;
        bf16x8 v = *reinterpret_cast<const bf16x8*>(A.Wt1 + (size_t)r * 128 + cx * 8);
        *reinterpret_cast<bf16x8*>(&Bs[r][cx * 8]) = v;
    }
    __syncthreads();
    {
        const int wr0 = (w >> 1) * 32;
        const int wc0 = (w & 1) * 64;
        f32x4 acc[2][4] = {};
#pragma unroll
        for (int ks = 0; ks < 4; ks++) {
            const int koff = ks * 32 + (lane >> 4) * 8;
            bf16x8 af[2], bfr[4];
#pragma unroll
            for (int mf = 0; mf < 2; mf++)
                af[mf] = *reinterpret_cast<const bf16x8*>(&As[wr0 + mf * 16 + (lane & 15)][koff]);
#pragma unroll
            for (int nf = 0; nf < 4; nf++)
                bfr[nf] = *reinterpret_cast<const bf16x8*>(&Bs[wc0 + nf * 16 + (lane & 15)][koff]);
#pragma unroll
            for (int mf = 0; mf < 2; mf++)
#pragma unroll
                for (int nf = 0; nf < 4; nf++)
                    acc[mf][nf] = __builtin_amdgcn_mfma_f32_16x16x32_bf16(af[mf], bfr[nf], acc[mf][nf], 0, 0, 0);
        }
        __syncthreads();
#pragma unroll
        for (int mf = 0; mf < 2; mf++)
#pragma unroll
            for (int r = 0; r < 4; r++) {
                int row = wr0 + mf * 16 + (lane >> 4) * 4 + r;
#pragma unroll
                for (int nf = 0; nf < 4; nf++) {
                    int colc = wc0 + nf * 16 + (lane & 15);
                    float v = fmaxf(acc[mf][nf][r] + A.b1[colc], 0.f);
                    As[row][colc] = __builtin_bit_cast(ushort_t, (__bf16)v);
                }
            }
#pragma unroll
        for (int t = 0; t < 4; t++) {
            int ch = t * 256 + tid;
            int r = ch >> 4, cx = ch & 15;
            bf16x8 v = *reinterpret_cast<const bf16x8*>(A.Wt2 + (size_t)r * 128 + cx * 8);
            *reinterpret_cast<bf16x8*>(&Bs[r][cx * 8]) = v;
        }
        __syncthreads();
    }
    const int wr2 = w * 16;
    f32x4 acc2[4] = {};
#pragma unroll
    for (int ks = 0; ks < 4; ks++) {
        const int koff = ks * 32 + (lane >> 4) * 8;
        bf16x8 a2 = *reinterpret_cast<const bf16x8*>(&As[wr2 + (lane & 15)][koff]);
#pragma unroll
        for (int nf = 0; nf < 4; nf++) {
            bf16x8 bf2 = *reinterpret_cast<const bf16x8*>(&Bs[nf * 16 + (lane & 15)][koff]);
            acc2[nf] = __builtin_amdgcn_mfma_f32_16x16x32_bf16(a2, bf2, acc2[nf], 0, 0, 0);
        }
    }
    int q = lane >> 4, c = lane & 15;
    bool full = (row0 + 63) < M;
    int g0 = batch[min(row0, M - 1)];
    int g1 = batch[min(row0 + 63, M - 1)];
    if (full && g0 == g1) {
        float s0 = acc2[0][0] + acc2[0][1] + acc2[0][2] + acc2[0][3];
        float s1 = acc2[1][0] + acc2[1][1] + acc2[1][2] + acc2[1][3];
        float s2 = acc2[2][0] + acc2[2][1] + acc2[2][2] + acc2[2][3];
        float s3 = acc2[3][0] + acc2[3][1] + acc2[3][2] + acc2[3][3];
        s0 += __shfl_xor(s0, 16); s0 += __shfl_xor(s0, 32);
        s1 += __shfl_xor(s1, 16); s1 += __shfl_xor(s1, 32);
        s2 += __shfl_xor(s2, 16); s2 += __shfl_xor(s2, 32);
        s3 += __shfl_xor(s3, 16); s3 += __shfl_xor(s3, 32);
        float v = (q & 2) ? ((q & 1) ? s3 : s2) : ((q & 1) ? s1 : s0);
        v += 16.f * A.b2[q * 16 + c];
        atomicAdd(&p[g0 * CDIM + q * 16 + c], v);
    } else {
        float b2v[4];
#pragma unroll
        for (int nf = 0; nf < 4; nf++) b2v[nf] = A.b2[nf * 16 + c];
#pragma unroll
        for (int r = 0; r < 4; r++) {
            int row = row0 + wr2 + q * 4 + r;
            if (row >= M) continue;
            int g = batch[row];
#pragma unroll
            for (int nf = 0; nf < 4; nf++)
                atomicAdd(&p[g * CDIM + nf * 16 + c], acc2[nf][r] + b2v[nf]);
        }
    }
    __syncthreads();
}

__device__ void d_final(int i, int tid, const MegaArgs& A) {
    if (tid >= 64) return;
    const float* p1 = A.p;
    const float* p2 = A.p + GDIM * CDIM;
    float s = 0.f;
    for (int g = 0; g < GDIM; ++g) s += p1[g * CDIM + i] * p2[g * CDIM + tid];
    A.out[i * CDIM + tid] = s;
}

// ================= cooperative mega-kernel =================

__global__ __launch_bounds__(256, 3) void k_mega(MegaArgs A) {
    cg::grid_group grid = cg::this_grid();
    __shared__ __align__(16) char smem[52224];
    const int bid = blockIdx.x, tid = threadIdx.x, G = A.nblk;

    // P0: setup + bucket histograms
    for (int u = bid; u < 226 + 2 * NCHB; u += G) {
        if (u < 226) d_setup(u, tid, A);
        else if (u < 226 + NCHB) d_bhist(u - 226, 0, tid, A, smem);
        else d_bhist(u - 226 - NCHB, 1, tid, A, smem);
        __syncthreads();
    }
    grid.sync();
    // P1: bscan + GEMM0 branch0
    if (bid == 0) d_bscan(0, tid, A, smem);
    else if (bid == 1) d_bscan(1, tid, A, smem);
    else for (int u = bid - 2; u < GEMM_TILES; u += G - 2) d_gemm_tile<true>(u, 0, tid, A, smem);
    grid.sync();
    // P2: part + GEMM0 branch1 (first part)
    if (bid < NCHB) { d_part(bid, 0, tid, A, smem); d_part(bid, 1, tid, A, smem); }
    else for (int u = bid - NCHB; u < 520; u += G - NCHB) d_gemm_tile<true>(u, 1, tid, A, smem);
    grid.sync();
    // P3: place + GEMM0 branch1 (rest)
    if (bid < NB) { d_place(bid, 0, tid, A, smem); d_place(bid, 1, tid, A, smem); }
    else for (int u = 520 + (bid - NB); u < GEMM_TILES; u += G - NB) d_gemm_tile<true>(u, 1, tid, A, smem);
    grid.sync();
    // P4: agg L0 b0 (full grid)
    for (int u = bid; u < AGG_UNITS; u += G) d_agg(u, 0, 0, tid, A);
    grid.sync();
    const int S = (G / 3) * 2;
    // P5: agg L0 b1 || GEMM1 b0
    if (bid < S) { for (int u = bid; u < AGG_UNITS; u += S) d_agg(u, 1, 0, tid, A); }
    else for (int u = bid - S; u < GEMM_TILES; u += G - S) d_gemm_tile<false>(u, 0, tid, A, smem);
    grid.sync();
    // P6: agg L1 b0 || GEMM1 b1
    if (bid < S) { for (int u = bid; u < AGG_UNITS; u += S) d_agg(u, 0, 1, tid, A); }
    else for (int u = bid - S; u < GEMM_TILES; u += G - S) d_gemm_tile<false>(u, 1, tid, A, smem);
    grid.sync();
    // P7: mlp b0 || agg L1 b1
    if (bid < S) { for (int u = bid; u < GEMM_TILES; u += S) d_mlp(u, 0, tid, A, smem); }
    else for (int u = bid - S; u < AGG_UNITS; u += G - S) d_agg(u, 1, 1, tid, A);
    grid.sync();
    // P8: mlp b1 (full grid)
    for (int u = bid; u < GEMM_TILES; u += G) d_mlp(u, 1, tid, A, smem);
    grid.sync();
    // P9: final
    if (bid < CDIM) d_final(bid, tid, A);
}

// ================= fallback multi-kernel path (round-9 proven) =================

__global__ __launch_bounds__(256) void k_setup(const float* __restrict__ convW,
                                               const float* __restrict__ w1,
                                               const float* __restrict__ w2,
                                               const float* __restrict__ a_s,
                                               const float* __restrict__ a_d,
                                               __bf16* __restrict__ WtC, __bf16* __restrict__ Wt1,
                                               __bf16* __restrict__ Wt2, float* __restrict__ Wa,
                                               float* __restrict__ p) {
    MegaArgs A = {};
    A.convW = convW; A.w1 = w1; A.w2 = w2; A.att_s = a_s; A.att_d = a_d;
    A.WtC = WtC; A.Wt1 = Wt1; A.Wt2 = Wt2; A.Wa = Wa; A.p = p;
    d_setup(blockIdx.x, threadIdx.x, A);
}

__global__ __launch_bounds__(256) void k_bhist(const int* ei0, const int* ei1, int* bcnt) {
    __shared__ char smem[1024];
    MegaArgs A = {}; A.ei0 = ei0; A.ei1 = ei1; A.bcnt = bcnt;
    d_bhist(blockIdx.x, blockIdx.y, threadIdx.x, A, smem);
}

__global__ __launch_bounds__(256) void k_bscan(const int* bcnt, int* boff, int* bcur) {
    __shared__ char smem[1024];
    MegaArgs A = {}; A.bcnt = (int*)bcnt; A.boff = boff; A.bcur = bcur;
    d_bscan(blockIdx.y, threadIdx.x, A, smem);
}

__global__ __launch_bounds__(256) void k_part(const int* ei0, const int* ei1, int* bcur,
                                              unsigned int* part) {
    __shared__ char smem[13312];
    MegaArgs A = {}; A.ei0 = ei0; A.ei1 = ei1; A.bcur = bcur; A.part = part;
    d_part(blockIdx.x, blockIdx.y, threadIdx.x, A, smem);
}

__global__ __launch_bounds__(256) void k_place(const unsigned int* part, const int* boff,
                                               int* row_ptr, int* col) {
    __shared__ char smem[1024];
    MegaArgs A = {}; A.part = (unsigned int*)part; A.boff = (int*)boff;
    A.row_ptr = row_ptr; A.col = col;
    d_place(blockIdx.x, blockIdx.y, threadIdx.x, A, smem);
}

template <bool AF32>
__global__ __launch_bounds__(256) void k_gemm_conv(MegaArgs A) {
    __shared__ __align__(16) char smem[52224];
    d_gemm_tile<AF32>(blockIdx.x, blockIdx.y, threadIdx.x, A, smem);
}

__global__ __launch_bounds__(256) void k_gat_agg(MegaArgs A, int layer) {
    d_agg(blockIdx.x, blockIdx.y, layer, threadIdx.x, A);
}

__global__ __launch_bounds__(256) void k_mlp_pool(MegaArgs A) {
    __shared__ __align__(16) char smem[52224];
    d_mlp(blockIdx.x, blockIdx.y, threadIdx.x, A, smem);
}

__global__ __launch_bounds__(64) void k_final(MegaArgs A) {
    d_final(blockIdx.x, threadIdx.x, A);
}

// ================= host side =================

static inline size_t align_up(size_t x, size_t a) { return (x + a - 1) & ~(a - 1); }

struct Ws {
    __bf16 *Hb, *Yb, *WtC, *Wt1, *Wt2;
    float *alpha_s, *alpha_d, *Wa, *p;
    int *row_ptr, *col, *bcnt, *boff, *bcur;
    unsigned int* part;
    size_t need;
};

static Ws carve(void* ws) {
    char* p = (char*)ws;
    size_t off = 0;
    Ws w;
    auto take = [&](size_t bytes) {
        char* r = p + off;
        off = align_up(off + bytes, 256);
        return r;
    };
    w.Hb = (__bf16*)take((size_t)2 * NNODES * HDIM * 2);
    w.Yb = (__bf16*)take((size_t)2 * NNODES * HDIM * 2);
    w.alpha_s = (float*)take((size_t)2 * NNODES * 4);
    w.alpha_d = (float*)take((size_t)2 * NNODES * 4);
    w.col = (int*)take((size_t)2 * NTOT * 4);
    w.part = (unsigned int*)take((size_t)2 * NEDGES * 4);
    w.row_ptr = (int*)take((size_t)2 * (NNODES + 1) * 4);
    w.bcnt = (int*)take((size_t)2 * NB * 4);
    w.boff = (int*)take((size_t)2 * (NB + 1) * 4);
    w.bcur = (int*)take((size_t)2 * NB * 4);
    w.WtC = (__bf16*)take((size_t)2 * HDIM * HDIM * 2);
    w.Wt1 = (__bf16*)take((size_t)HDIM * HDIM * 2);
    w.Wt2 = (__bf16*)take((size_t)HDIM * CDIM * 2);
    w.Wa = (float*)take((size_t)512 * 4);
    w.p = (float*)take((size_t)2 * GDIM * CDIM * 4);
    w.need = off;
    return w;
}

extern "C" void kernel_launch(void* const* d_in, const int* in_sizes, int n_in, void* d_out,
                              int out_size, void* d_ws, size_t ws_size, hipStream_t stream) {
    MegaArgs A;
    A.x0 = (const float*)d_in[0];
    A.x1 = (const float*)d_in[1];
    A.convW = (const float*)d_in[2];
    A.att_s = (const float*)d_in[3];
    A.att_d = (const float*)d_in[4];
    A.conv_b = (const float*)d_in[5];
    A.w1 = (const float*)d_in[6];
    A.b1 = (const float*)d_in[7];
    A.w2 = (const float*)d_in[8];
    A.b2 = (const float*)d_in[9];
    A.ei0 = (const int*)d_in[10];
    A.bat0 = (const int*)d_in[11];
    A.ei1 = (const int*)d_in[12];
    A.bat1 = (const int*)d_in[13];
    A.out = (float*)d_out;

    Ws w = carve(d_ws);
    A.Hb = w.Hb; A.Yb = w.Yb; A.WtC = w.WtC; A.Wt1 = w.Wt1; A.Wt2 = w.Wt2;
    A.alpha_s = w.alpha_s; A.alpha_d = w.alpha_d; A.Wa = w.Wa; A.p = w.p;
    A.row_ptr = w.row_ptr; A.col = w.col; A.bcnt = w.bcnt; A.boff = w.boff; A.bcur = w.bcur;
    A.part = w.part;

    hipMemsetAsync(w.bcnt, 0, (size_t)2 * NB * 4, stream);

    // try cooperative mega-kernel
    int nbpc = 0;
    hipError_t qe = hipOccupancyMaxActiveBlocksPerMultiprocessor(&nbpc, (const void*)k_mega, 256, 0);
    int G = (qe == hipSuccess) ? nbpc * 256 : 0;
    if (G > 768) G = 768;
    bool coop = (G >= 384);
    if (coop) {
        A.nblk = G;
        void* args[] = {&A};
        hipError_t le = hipLaunchCooperativeKernel((void*)k_mega, dim3(G), dim3(256), args, 0, stream);
        if (le != hipSuccess) coop = false;
    }
    if (!coop) {
        // fallback: proven multi-kernel pipeline (both branches via grid-y)
        A.nblk = 0;
        k_setup<<<226, 256, 0, stream>>>(A.convW, A.w1, A.w2, A.att_s, A.att_d,
                                         w.WtC, w.Wt1, w.Wt2, w.Wa, w.p);
        dim3 gC(NCHB, 2), gB(NB, 2), g1(1, 2);
        dim3 gW(AGG_UNITS, 2), gG(GEMM_TILES, 2);
        k_bhist<<<gC, 256, 0, stream>>>(A.ei0, A.ei1, w.bcnt);
        k_bscan<<<g1, 256, 0, stream>>>(w.bcnt, w.boff, w.bcur);
        k_part<<<gC, 256, 0, stream>>>(A.ei0, A.ei1, w.bcur, w.part);
        k_place<<<gB, 256, 0, stream>>>(w.part, w.boff, w.row_ptr, w.col);
        k_gemm_conv<true><<<gG, 256, 0, stream>>>(A);
        k_gat_agg<<<gW, 256, 0, stream>>>(A, 0);
        k_gemm_conv<false><<<gG, 256, 0, stream>>>(A);
        k_gat_agg<<<gW, 256, 0, stream>>>(A, 1);
        k_mlp_pool<<<gG, 256, 0, stream>>>(A);
        k_final<<<CDIM, 64, 0, stream>>>(A);
    }
}